// Round 1
// 664.657 us; speedup vs baseline: 1.0033x; 1.0033x over previous
//
#include <hip/hip_runtime.h>
#include <math.h>
#include <stdint.h>

// Geometry constants
#define VIEWS 512
#define NDET 736
#define NX 256
#define NY 256
#define EXTENT 2
#define SINO_LEN (VIEWS * NDET)          // 376832
#define NVOX (NX * NY)                   // 65536
#define PER_VOX (VIEWS * EXTENT)         // 1024

// SCALE = (2*pi - 0) / (2 * VIEWS * EXTENT) = pi / 1024
__device__ __constant__ float kScale = (float)(M_PI / 1024.0);

typedef int   v4i __attribute__((ext_vector_type(4)));
typedef float v4f __attribute__((ext_vector_type(4)));

// Raw buffer load with cache-policy aux bits (CK-style direct intrinsic
// declaration — always available in hipcc/clang). aux=1 -> SC0 on gfx950:
// the load does NOT allocate in the per-CU L1; it is serviced from L2,
// where x (1.47 MB) is resident per-XCD. This removes the per-gather
// L1 tag-allocate + 64B line-fill + evict overhead that the random
// 4B gathers pay for a ~2% L1 hit rate.
extern "C" __device__ float
__bp_raw_buffer_load_f32(v4i rsrc, int voffset, int soffset, int aux)
    __asm("llvm.amdgcn.raw.buffer.load.f32");

// One wave (64 lanes) per voxel. Each lane handles 16 elements:
// Phase 1: 4 x int4 index loads + 4 x float4 weight loads (coalesced,
//          16B/lane) all issued up front for max MLP.
// Phase 2: 16 scattered sc0 buffer-loads from x (L2-resident).
// Phase 3: FMAs, 6-step shuffle reduction; lane 0 writes flipped output.
__global__ __launch_bounds__(256) void backproj_kernel(
    const float* __restrict__ x,      // [SINO_LEN]
    const float* __restrict__ weight, // [NVOX * PER_VOX]
    const float* __restrict__ bias,   // [NVOX]
    const int*   __restrict__ indices,// [NVOX * PER_VOX]
    float*       __restrict__ out)    // [NVOX]
{
    const int wave_in_block = threadIdx.x >> 6;
    const int lane          = threadIdx.x & 63;
    const int v             = blockIdx.x * 4 + wave_in_block; // voxel id
    const size_t base       = (size_t)v * PER_VOX;

    // SRSRC for x: stride=0 raw buffer, num_records = byte size.
    v4i xr;
    xr.x = (int)(uint32_t)(uintptr_t)x;
    xr.y = (int)(uint32_t)((uint64_t)(uintptr_t)x >> 32);
    xr.z = SINO_LEN * 4;
    xr.w = 0x00020000;

    const v4i* ip = (const v4i*)(indices + base);
    const v4f* wp = (const v4f*)(weight + base);

    // Phase 1: issue all streaming loads up front (8 outstanding VMEM).
    v4i i4[4];
    v4f w4[4];
#pragma unroll
    for (int k = 0; k < 4; ++k) i4[k] = ip[lane + k * 64];
#pragma unroll
    for (int k = 0; k < 4; ++k) w4[k] = wp[lane + k * 64];

    // Phase 2: issue all 16 gathers (sc0: L1-bypass, L2-serviced).
    float g[16];
#pragma unroll
    for (int k = 0; k < 4; ++k) {
        g[4 * k + 0] = __bp_raw_buffer_load_f32(xr, i4[k].x << 2, 0, 1);
        g[4 * k + 1] = __bp_raw_buffer_load_f32(xr, i4[k].y << 2, 0, 1);
        g[4 * k + 2] = __bp_raw_buffer_load_f32(xr, i4[k].z << 2, 0, 1);
        g[4 * k + 3] = __bp_raw_buffer_load_f32(xr, i4[k].w << 2, 0, 1);
    }

    // Phase 3: weighted sum.
    float s = 0.0f;
#pragma unroll
    for (int k = 0; k < 4; ++k) {
        s += g[4 * k + 0] * w4[k].x;
        s += g[4 * k + 1] * w4[k].y;
        s += g[4 * k + 2] * w4[k].z;
        s += g[4 * k + 3] * w4[k].w;
    }

    // wave-64 reduction
#pragma unroll
    for (int off = 32; off > 0; off >>= 1)
        s += __shfl_down(s, off, 64);

    if (lane == 0) {
        // flip over both spatial axes: flattened index reversal
        out[NVOX - 1 - v] = bias[v] + kScale * s;
    }
}

extern "C" void kernel_launch(void* const* d_in, const int* in_sizes, int n_in,
                              void* d_out, int out_size, void* d_ws, size_t ws_size,
                              hipStream_t stream) {
    const float* x       = (const float*)d_in[0];
    const float* weight  = (const float*)d_in[1];
    const float* bias    = (const float*)d_in[2];
    const int*   indices = (const int*)d_in[3];
    float*       out     = (float*)d_out;

    // 4 waves per block, 1 voxel per wave
    const int blocks = NVOX / 4; // 16384
    backproj_kernel<<<blocks, 256, 0, stream>>>(x, weight, bias, indices, out);
}